// Round 9
// baseline (383.879 us; speedup 1.0000x reference)
//
#include <hip/hip_runtime.h>
#include <stdint.h>

typedef short short8 __attribute__((ext_vector_type(8)));
typedef float float4v __attribute__((ext_vector_type(4)));
typedef unsigned long long ull;

// Sizes fixed: N=8, M=512, D=64, B=8192. Block: one n, 128 b-rows, 8 waves.
// mfma(E, X): C rows = m-local (kg*4+j), cols = b (l15).
// ROUND 9: occupancy attack. E staged in 128-row QUARTERS (16 KB) so total
// LDS = 32 KB -> 4 blocks/CU -> 32 waves/CU (was 80 KB -> 2 blocks -> 16).
// Sweep1 writes unnormalized y to gy scratch (coalesced 8B/lane); sweep2 is
// zero-transcendental (recompute s via MFMA, read y back, scale by rz2).
//
// FAST LDS map (32 KB):
//   [0, 16384)      E quarter bf16 [128 m][128 B], XOR-swizzled (byte ^= (m&7)<<4)
//                   (finale: avg f32 [8][512] overlays, 16 KB)
//   [16384, 32768)  AUX: prologue X-stage 16 KB; then esq f32[512] @16384,
//                   samp 8 x 1 KB @18432, kls @26624
#define ESQ_OFF   16384
#define SAMP_OFF  18432
#define KLS_OFF   26624
#define LDS_FAST  32768

// fallback (round-6/8 style, full-E 80 KB)
#define R2      65536
#define LDS_SZ  81920

__device__ __forceinline__ unsigned cvtpk(float a, float b){
  unsigned d;
  asm("v_cvt_pk_bf16_f32 %0, %1, %2" : "=v"(d) : "v"(a), "v"(b));
  return d;
}
__device__ __forceinline__ unsigned short f2bf(float f){
  unsigned u = __float_as_uint(f);
  return (unsigned short)((u + 0x7FFFu + ((u >> 16) & 1u)) >> 16);
}
__device__ __forceinline__ float bfLO(unsigned r){ return __uint_as_float(r << 16); }
__device__ __forceinline__ float bfHI(unsigned r){ return __uint_as_float(r & 0xffff0000u); }

template<int OFF>
__device__ __forceinline__ ull tr16(unsigned a){
  ull d;
  asm volatile("ds_read_b64_tr_b16 %0, %1 offset:%c2" : "=v"(d) : "v"(a), "i"(OFF));
  return d;
}
__device__ __forceinline__ short8 mk8(ull lo, ull hi){
  union { ull q[2]; short8 v; } u; u.q[0] = lo; u.q[1] = hi; return u.v;
}

// stage one 128-row quarter of E (bf16, swizzled) into smem[0..16384)
__device__ __forceinline__ void stage_eq(char* smem, const float* ge, int n, int q, int tid){
  const int r = tid >> 2, qq = tid & 3;
  const float* src = ge + ((size_t)(n * 512 + q * 128 + r)) * 64 + qq * 16;
  char* dst = smem + r * 128;
  const unsigned sw = (unsigned)((r & 7) << 4);
#pragma unroll
  for (int h = 0; h < 2; ++h) {
    float4 a = *(const float4*)(src + h * 8);
    float4 b = *(const float4*)(src + h * 8 + 4);
    uint4 v = { cvtpk(a.x, a.y), cvtpk(a.z, a.w), cvtpk(b.x, b.y), cvtpk(b.z, b.w) };
    *(uint4*)(dst + (((unsigned)((qq * 2 + h) * 16)) ^ sw)) = v;
  }
}

// ---------------- phase-B chunk tail (layout-agnostic) ----------------------
#define PHASE_B_TAIL(cvar)                                                     \
    asm volatile("s_waitcnt lgkmcnt(0)" ::: "memory");                         \
    __builtin_amdgcn_sched_barrier(0);                                         \
    const short8 avA = *(const short8*)(sampc + l15 * 32 + (kg & 1) * 16);     \
    const short8 avB = *(const short8*)(sampc + 512 + l15 * 32 + (kg & 1) * 16); \
    ull alo = tr16<0>(trA),  ahi = tr16<512>(trA);                             \
    ull b0l = tr16<0>(trB0), b0h = tr16<2048>(trB0);                           \
    ull b1l = tr16<0>(trB1), b1h = tr16<2048>(trB1);                           \
    ull b2l = tr16<0>(trB2), b2h = tr16<2048>(trB2);                           \
    ull b3l = tr16<0>(trB3), b3h = tr16<2048>(trB3);                           \
    asm volatile("s_waitcnt lgkmcnt(0)" ::: "memory");                         \
    __builtin_amdgcn_sched_barrier(0);                                         \
    const unsigned onv = ((l15 == (cvar)) && (kg < 2)) ? 0x3F803F80u : 0u;     \
    union { unsigned u[4]; short8 v; } bs;                                     \
    bs.u[0] = onv; bs.u[1] = onv; bs.u[2] = onv; bs.u[3] = onv;                \
    short8 aa = mk8(alo, ahi);                                                 \
    qacc0 = __builtin_amdgcn_mfma_f32_16x16x32_bf16(aa, mk8(b0l, b0h), qacc0, 0, 0, 0); \
    qacc1 = __builtin_amdgcn_mfma_f32_16x16x32_bf16(aa, mk8(b1l, b1h), qacc1, 0, 0, 0); \
    qacc2 = __builtin_amdgcn_mfma_f32_16x16x32_bf16(aa, mk8(b2l, b2h), qacc2, 0, 0, 0); \
    qacc3 = __builtin_amdgcn_mfma_f32_16x16x32_bf16(aa, mk8(b3l, b3h), qacc3, 0, 0, 0); \
    avgA  = __builtin_amdgcn_mfma_f32_16x16x32_bf16(avA, bs.v, avgA, 0, 0, 0); \
    avgB  = __builtin_amdgcn_mfma_f32_16x16x32_bf16(avB, bs.v, avgB, 0, 0, 0); \
    trB0 += 4096; trB1 += 4096; trB2 += 4096; trB3 += 4096;

// ============================ FAST kernel (32 KB LDS, 4 blocks/CU) ==========
extern "C" __global__ void __launch_bounds__(512, 8)
vq_main_ws(const float* __restrict__ gx, const float* __restrict__ ge,
           const float* __restrict__ gu, const float* __restrict__ gtau,
           float* __restrict__ gq, float* __restrict__ glg,
           ull* __restrict__ gy,
           float* __restrict__ ws_avg, float* __restrict__ ws_kl)
{
  extern __shared__ char smem[];
  const int tid = threadIdx.x;
  const int n   = blockIdx.x >> 6;
  const int b0  = (blockIdx.x & 63) * 128;

  // ---- prologue: private full-row esq read; X-stage into AUX ----
  float esq_reg = 0.f;
  {
    const float* src = ge + (size_t)(n * 512 + tid) * 64;
#pragma unroll
    for (int c8 = 0; c8 < 8; ++c8) {
      float4 a = *(const float4*)(src + c8 * 8);
      float4 b = *(const float4*)(src + c8 * 8 + 4);
      esq_reg += a.x*a.x + a.y*a.y + a.z*a.z + a.w*a.w
               + b.x*b.x + b.y*b.y + b.z*b.z + b.w*b.w;
    }
  }
  {
    const int r = tid >> 2, qq = tid & 3;
    const float* src = gx + (size_t)(b0 + r) * 512 + n * 64 + qq * 16;
    char* dst = smem + ESQ_OFF + r * 128;     // X-stage overlays AUX
    const unsigned sw = (unsigned)((r & 7) << 4);
#pragma unroll
    for (int h = 0; h < 2; ++h) {
      float4 a = *(const float4*)(src + h * 8);
      float4 b = *(const float4*)(src + h * 8 + 4);
      uint4 v = { cvtpk(a.x, a.y), cvtpk(a.z, a.w), cvtpk(b.x, b.y), cvtpk(b.z, b.w) };
      *(uint4*)(dst + (((unsigned)((qq * 2 + h) * 16)) ^ sw)) = v;
    }
  }
  __syncthreads();                                    // bar1

  const int lane = tid & 63;
  const int w    = tid >> 6;
  const int l15  = lane & 15;
  const int kg   = lane >> 4;
  const unsigned swl = (unsigned)((l15 & 7) << 4);

  const char* xrow = smem + ESQ_OFF + (w * 16 + l15) * 128;
  const short8 xb0 = *(const short8*)(xrow + (((unsigned)(kg * 16)) ^ swl));
  const short8 xb1 = *(const short8*)(xrow + (((unsigned)(64 + kg * 16)) ^ swl));
  __syncthreads();                                    // bar2: X area free
  ((float*)(smem + ESQ_OFF))[tid] = esq_reg;          // esq[512]
  stage_eq(smem, ge, n, 0, tid);                      // E quarter 0
  __syncthreads();                                    // bar3

  const char* erow = smem + l15 * 128;
  const unsigned eo0 = ((unsigned)(kg * 16)) ^ swl;
  const unsigned eo1 = ((unsigned)(64 + kg * 16)) ^ swl;
  const float* esqp = (const float*)(smem + ESQ_OFF);

  const float tauv = gtau[0];
  const float invtau = 1.0f / tauv;
  const bool tau1 = (tauv == 1.0f);
  const float4* up4 = (const float4*)(gu + (size_t)n * 4194304
                     + (size_t)(b0 + w * 16 + l15) * 512 + kg * 4);
  ull* gyw = gy + ((size_t)blockIdx.x * 8 + w) * 2048;   // 32 tiles x 64 lanes

  // ---- sweep 1 (4 quarters x 8 tiles): Z, Wk, Z2; y_un -> gy ----
  float Z = 0.f, Wk = 0.f, Z2 = 0.f;

#define S1_BODY(T, LT, YE0, YE1, YE2, YE3)                                     \
    {                                                                          \
      short8 eb0 = *(const short8*)(erow + (LT) * 2048 + eo0);                 \
      short8 eb1 = *(const short8*)(erow + (LT) * 2048 + eo1);                 \
      float4v d = (float4v){0.f, 0.f, 0.f, 0.f};                               \
      d = __builtin_amdgcn_mfma_f32_16x16x32_bf16(eb0, xb0, d, 0, 0, 0);       \
      d = __builtin_amdgcn_mfma_f32_16x16x32_bf16(eb1, xb1, d, 0, 0, 0);       \
      const float4 eq = *(const float4*)(esqp + (T) * 16 + kg * 4);            \
      const float s0 = 2.f * d[0] - eq.x;                                      \
      const float s1 = 2.f * d[1] - eq.y;                                      \
      const float s2 = 2.f * d[2] - eq.z;                                      \
      const float s3 = 2.f * d[3] - eq.w;                                      \
      const float e0 = __expf(s0), e1 = __expf(s1);                            \
      const float e2 = __expf(s2), e3 = __expf(s3);                            \
      Z  += (e0 + e1) + (e2 + e3);                                             \
      Wk += e0 * s0 + e1 * s1 + e2 * s2 + e3 * s3;                             \
      const float4 uu = Pa;                                                    \
      Pa = Pb; Pb = Pc; Pc = Pd;                                               \
      if ((T) < 28) Pd = up4[((T) + 4) * 4];                                   \
      const float l0 = -__logf(uu.x), l1 = -__logf(uu.y);                      \
      const float l2 = -__logf(uu.z), l3 = -__logf(uu.w);                      \
      const float y0 = (YE0), y1 = (YE1);                                      \
      const float y2 = (YE2), y3 = (YE3);                                      \
      const unsigned pk0 = cvtpk(y0, y1);                                      \
      const unsigned pk1 = cvtpk(y2, y3);                                      \
      gyw[(T) * 64 + lane] = (ull)pk0 | ((ull)pk1 << 32);                      \
      Z2 += (y0 + y1) + (y2 + y3);                                             \
    }

#define SWEEP1(YE0, YE1, YE2, YE3)                                             \
  {                                                                            \
    float4 Pa = up4[0], Pb = up4[4], Pc = up4[8], Pd = up4[12];                \
    _Pragma("unroll")                                                          \
    for (int q = 0; q < 4; ++q) {                                              \
      if (q > 0) {                                                             \
        __syncthreads();                                                       \
        stage_eq(smem, ge, n, q, tid);                                         \
        __syncthreads();                                                       \
      }                                                                        \
      _Pragma("unroll")                                                        \
      for (int lt = 0; lt < 8; ++lt) {                                         \
        const int t = q * 8 + lt;                                              \
        S1_BODY(t, lt, YE0, YE1, YE2, YE3)                                     \
      }                                                                        \
    }                                                                          \
  }

  if (tau1) {
    SWEEP1(e0 * __builtin_amdgcn_rcpf(l0), e1 * __builtin_amdgcn_rcpf(l1),
           e2 * __builtin_amdgcn_rcpf(l2), e3 * __builtin_amdgcn_rcpf(l3))
  } else {
    SWEEP1(__expf((s0 - __logf(l0)) * invtau), __expf((s1 - __logf(l1)) * invtau),
           __expf((s2 - __logf(l2)) * invtau), __expf((s3 - __logf(l3)) * invtau))
  }
#undef SWEEP1
#undef S1_BODY

  Z  += __shfl_xor(Z, 16);  Z  += __shfl_xor(Z, 32);
  Wk += __shfl_xor(Wk, 16); Wk += __shfl_xor(Wk, 32);
  Z2 += __shfl_xor(Z2, 16); Z2 += __shfl_xor(Z2, 32);
  const float lse = __logf(Z);
  const float logM = 6.2383246250395075f;
  float klrow = Wk * __builtin_amdgcn_rcpf(Z) - lse + logM;
  const float rz2 = __builtin_amdgcn_rcpf(Z2);

  // ---- sweep 2 (4 quarters x 4 chunks): zero-trans; lp -> glg; y*rz2 -> samp ----
  float4v* lp4 = (float4v*)(glg + (size_t)(b0 + w * 16 + l15) * 4096 + n * 512 + kg * 4);
  ushort* sampw = (ushort*)(smem + SAMP_OFF + w * 1024);   // [32 m][16 r]
  const char* sampc = (const char*)sampw;
  const unsigned trA = (unsigned)(uintptr_t)sampw
                     + (unsigned)(kg * 128 + (l15 >> 2) * 32 + (l15 & 3) * 8);
  const int mrow = kg * 4 + (l15 >> 2);
  const unsigned ebase = (unsigned)(uintptr_t)smem + (unsigned)(mrow * 128);
  const unsigned msw = ((unsigned)(mrow & 7)) << 4;
  const unsigned tb0 = ebase + ((unsigned)(  0 + (l15 & 3) * 8) ^ msw);
  const unsigned tb1 = ebase + ((unsigned)( 32 + (l15 & 3) * 8) ^ msw);
  const unsigned tb2 = ebase + ((unsigned)( 64 + (l15 & 3) * 8) ^ msw);
  const unsigned tb3 = ebase + ((unsigned)( 96 + (l15 & 3) * 8) ^ msw);

  float4v qacc0 = (float4v){0.f,0.f,0.f,0.f};
  float4v qacc1 = (float4v){0.f,0.f,0.f,0.f};
  float4v qacc2 = (float4v){0.f,0.f,0.f,0.f};
  float4v qacc3 = (float4v){0.f,0.f,0.f,0.f};
  float4v avgA  = (float4v){0.f,0.f,0.f,0.f};
  float4v avgB  = (float4v){0.f,0.f,0.f,0.f};

  __syncthreads();                                    // all waves done with E q3
  stage_eq(smem, ge, n, 0, tid);                      // re-stage quarter 0
  __syncthreads();

  // order the same-lane global RAW (gy stores -> gy loads)
  asm volatile("s_waitcnt vmcnt(0)" ::: "memory");
  ull Ya[4] = { gyw[lane], gyw[64 + lane], gyw[128 + lane], gyw[192 + lane] };

#pragma unroll
  for (int q = 0; q < 4; ++q) {
    if (q > 0) {
      __syncthreads();
      stage_eq(smem, ge, n, q, tid);
      __syncthreads();
    }
    unsigned trB0 = tb0, trB1 = tb1, trB2 = tb2, trB3 = tb3;
#pragma unroll
    for (int lc = 0; lc < 4; ++lc) {
      const int c = q * 4 + lc;
#pragma unroll
      for (int th = 0; th < 2; ++th) {
        const int t = c * 2 + th;
        const int lt = lc * 2 + th;
        short8 eb0 = *(const short8*)(erow + lt * 2048 + eo0);
        short8 eb1 = *(const short8*)(erow + lt * 2048 + eo1);
        float4v d = (float4v){0.f, 0.f, 0.f, 0.f};
        d = __builtin_amdgcn_mfma_f32_16x16x32_bf16(eb0, xb0, d, 0, 0, 0);
        d = __builtin_amdgcn_mfma_f32_16x16x32_bf16(eb1, xb1, d, 0, 0, 0);
        const float4 eq = *(const float4*)(esqp + t * 16 + kg * 4);
        float4v lpv = { 2.f * d[0] - eq.x - lse, 2.f * d[1] - eq.y - lse,
                        2.f * d[2] - eq.z - lse, 2.f * d[3] - eq.w - lse };
        lp4[t * 4] = lpv;
        const ull yc = Ya[t & 3];
        if (t < 28) Ya[t & 3] = gyw[(t + 4) * 64 + lane];
        const unsigned pk0 = (unsigned)yc;
        const unsigned pk1 = (unsigned)(yc >> 32);
        const unsigned q0 = cvtpk(bfLO(pk0) * rz2, bfHI(pk0) * rz2);
        const unsigned q1 = cvtpk(bfLO(pk1) * rz2, bfHI(pk1) * rz2);
        sampw[(th * 16 + kg * 4 + 0) * 16 + l15] = (ushort)q0;
        sampw[(th * 16 + kg * 4 + 1) * 16 + l15] = (ushort)(q0 >> 16);
        sampw[(th * 16 + kg * 4 + 2) * 16 + l15] = (ushort)q1;
        sampw[(th * 16 + kg * 4 + 3) * 16 + l15] = (ushort)(q1 >> 16);
      }
      PHASE_B_TAIL(c)
    }
  }

  // ---- store quantized (row b = kg*4+j, col d = l15) ----
  {
    const size_t qb = (size_t)(b0 + w * 16 + kg * 4) * 512 + n * 64 + l15;
#pragma unroll
    for (int j = 0; j < 4; ++j) {
      gq[qb + (size_t)j * 512 +  0] = qacc0[j];
      gq[qb + (size_t)j * 512 + 16] = qacc1[j];
      gq[qb + (size_t)j * 512 + 32] = qacc2[j];
      gq[qb + (size_t)j * 512 + 48] = qacc3[j];
    }
  }

  klrow += __shfl_xor(klrow, 1); klrow += __shfl_xor(klrow, 2);
  klrow += __shfl_xor(klrow, 4); klrow += __shfl_xor(klrow, 8);

  __syncthreads();                                    // bar: E + samp dead
  float* avgl = (float*)smem;                         // [8][512] = 16 KB @0
  float* kls  = (float*)(smem + KLS_OFF);
  if (lane == 0) kls[w] = klrow;
  *(float4v*)(avgl + w * 512 + l15 * 32 + kg * 4)      = avgA;
  *(float4v*)(avgl + w * 512 + l15 * 32 + 16 + kg * 4) = avgB;
  __syncthreads();
  {
    float s = 0.f;
#pragma unroll
    for (int ww = 0; ww < 8; ++ww) s += avgl[ww * 512 + tid];
    ws_avg[(size_t)blockIdx.x * 512 + tid] = s;
    if (tid == 0) {
      float k = 0.f;
#pragma unroll
      for (int i = 0; i < 8; ++i) k += kls[i];
      ws_kl[blockIdx.x] = k;
    }
  }
}

// ===================== FALLBACK kernel (round-6 style, 80 KB LDS) ===========
extern "C" __global__ void __launch_bounds__(512, 4)
vq_main_fb(const float* __restrict__ gx, const float* __restrict__ ge,
           const float* __restrict__ gu, const float* __restrict__ gtau,
           float* __restrict__ gq, float* __restrict__ glg,
           float* __restrict__ ws_avg, float* __restrict__ ws_kl)
{
  extern __shared__ char smem[];
  const int tid = threadIdx.x;
  const int n   = blockIdx.x >> 6;
  const int b0  = (blockIdx.x & 63) * 128;

  float esq_reg = 0.f;
  {
    const int m = tid;
    const float* src = ge + (size_t)(n * 512 + m) * 64;
    char* dst = smem + m * 128;
    const unsigned sw = (unsigned)((m & 7) << 4);
#pragma unroll
    for (int c = 0; c < 8; ++c) {
      float4 a = *(const float4*)(src + c * 8);
      float4 b = *(const float4*)(src + c * 8 + 4);
      esq_reg += a.x*a.x + a.y*a.y + a.z*a.z + a.w*a.w
               + b.x*b.x + b.y*b.y + b.z*b.z + b.w*b.w;
      uint4 v = { cvtpk(a.x, a.y), cvtpk(a.z, a.w), cvtpk(b.x, b.y), cvtpk(b.z, b.w) };
      *(uint4*)(dst + (((unsigned)(c * 16)) ^ sw)) = v;
    }
  }
  {
    const int r = tid >> 2, qq = tid & 3;
    const float* src = gx + (size_t)(b0 + r) * 512 + n * 64 + qq * 16;
    char* dst = smem + R2 + r * 128;
    const unsigned sw = (unsigned)((r & 7) << 4);
#pragma unroll
    for (int h = 0; h < 2; ++h) {
      float4 a = *(const float4*)(src + h * 8);
      float4 b = *(const float4*)(src + h * 8 + 4);
      uint4 v = { cvtpk(a.x, a.y), cvtpk(a.z, a.w), cvtpk(b.x, b.y), cvtpk(b.z, b.w) };
      *(uint4*)(dst + (((unsigned)((qq * 2 + h) * 16)) ^ sw)) = v;
    }
  }
  __syncthreads();

  const int lane = tid & 63;
  const int w    = tid >> 6;
  const int l15  = lane & 15;
  const int kg   = lane >> 4;
  const unsigned swl = (unsigned)((l15 & 7) << 4);

  const char* xrow = smem + R2 + (w * 16 + l15) * 128;
  const short8 xb0 = *(const short8*)(xrow + (((unsigned)(kg * 16)) ^ swl));
  const short8 xb1 = *(const short8*)(xrow + (((unsigned)(64 + kg * 16)) ^ swl));
  __syncthreads();
  ((float*)(smem + R2))[tid] = esq_reg;
  __syncthreads();

  const char* erow = smem + l15 * 128;
  const unsigned eo0 = ((unsigned)(kg * 16)) ^ swl;
  const unsigned eo1 = ((unsigned)(64 + kg * 16)) ^ swl;
  const float* esqp = (const float*)(smem + R2);

  const float invtau = 1.0f / gtau[0];
  const float4* up4 = (const float4*)(gu + (size_t)n * 4194304
                     + (size_t)(b0 + w * 16 + l15) * 512 + kg * 4);

  float Z = 0.f, Wk = 0.f, Z2 = 0.f;
  {
    float4 Pa = up4[0], Pb = up4[4], Pc = up4[8], Pd = up4[12];
#pragma unroll
    for (int t = 0; t < 32; ++t) {
      short8 eb0 = *(const short8*)(erow + t * 2048 + eo0);
      short8 eb1 = *(const short8*)(erow + t * 2048 + eo1);
      float4v d = (float4v){0.f, 0.f, 0.f, 0.f};
      d = __builtin_amdgcn_mfma_f32_16x16x32_bf16(eb0, xb0, d, 0, 0, 0);
      d = __builtin_amdgcn_mfma_f32_16x16x32_bf16(eb1, xb1, d, 0, 0, 0);
      const float4 eq = *(const float4*)(esqp + t * 16 + kg * 4);
      const float s0 = 2.f * d[0] - eq.x;
      const float s1 = 2.f * d[1] - eq.y;
      const float s2 = 2.f * d[2] - eq.z;
      const float s3 = 2.f * d[3] - eq.w;
      const float e0 = __expf(s0), e1 = __expf(s1), e2 = __expf(s2), e3 = __expf(s3);
      Z  += (e0 + e1) + (e2 + e3);
      Wk += e0 * s0 + e1 * s1 + e2 * s2 + e3 * s3;
      const float4 uu = Pa;
      Pa = Pb; Pb = Pc; Pc = Pd;
      if (t < 28) Pd = up4[(t + 4) * 4];
      const float g0 = -__logf(-__logf(uu.x));
      const float g1 = -__logf(-__logf(uu.y));
      const float g2 = -__logf(-__logf(uu.z));
      const float g3 = -__logf(-__logf(uu.w));
      Z2 += __expf((s0 + g0) * invtau) + __expf((s1 + g1) * invtau)
          + __expf((s2 + g2) * invtau) + __expf((s3 + g3) * invtau);
    }
  }
  Z  += __shfl_xor(Z, 16);  Z  += __shfl_xor(Z, 32);
  Wk += __shfl_xor(Wk, 16); Wk += __shfl_xor(Wk, 32);
  Z2 += __shfl_xor(Z2, 16); Z2 += __shfl_xor(Z2, 32);
  const float lse = __logf(Z);
  const float logM = 6.2383246250395075f;
  float klrow = Wk * __builtin_amdgcn_rcpf(Z) - lse + logM;
  const float rz2 = __builtin_amdgcn_rcpf(Z2);

  float4v* lp4 = (float4v*)(glg + (size_t)(b0 + w * 16 + l15) * 4096 + n * 512 + kg * 4);
  ushort* sampw = (ushort*)(smem + R2 + 8192 + w * 1024);
  const char* sampc = (const char*)sampw;
  const unsigned trA = (unsigned)(uintptr_t)sampw
                     + (unsigned)(kg * 128 + (l15 >> 2) * 32 + (l15 & 3) * 8);
  const int mrow = kg * 4 + (l15 >> 2);
  const unsigned ebase = (unsigned)(uintptr_t)smem + (unsigned)(mrow * 128);
  const unsigned msw = ((unsigned)(mrow & 7)) << 4;
  unsigned trB0 = ebase + ((unsigned)(  0 + (l15 & 3) * 8) ^ msw);
  unsigned trB1 = ebase + ((unsigned)( 32 + (l15 & 3) * 8) ^ msw);
  unsigned trB2 = ebase + ((unsigned)( 64 + (l15 & 3) * 8) ^ msw);
  unsigned trB3 = ebase + ((unsigned)( 96 + (l15 & 3) * 8) ^ msw);

  float4v qacc0 = (float4v){0.f,0.f,0.f,0.f};
  float4v qacc1 = (float4v){0.f,0.f,0.f,0.f};
  float4v qacc2 = (float4v){0.f,0.f,0.f,0.f};
  float4v qacc3 = (float4v){0.f,0.f,0.f,0.f};
  float4v avgA  = (float4v){0.f,0.f,0.f,0.f};
  float4v avgB  = (float4v){0.f,0.f,0.f,0.f};

  float4 P0 = up4[0], P1 = up4[4], P2 = up4[8], P3 = up4[12];
#pragma unroll
  for (int c = 0; c < 16; ++c) {
    const float4 cu0 = P0, cu1 = P1;
    P0 = P2; P1 = P3;
    if (c < 14) { P2 = up4[(2 * c + 4) * 4]; P3 = up4[(2 * c + 5) * 4]; }
#pragma unroll
    for (int th = 0; th < 2; ++th) {
      const int t = c * 2 + th;
      short8 eb0 = *(const short8*)(erow + t * 2048 + eo0);
      short8 eb1 = *(const short8*)(erow + t * 2048 + eo1);
      float4v d = (float4v){0.f, 0.f, 0.f, 0.f};
      d = __builtin_amdgcn_mfma_f32_16x16x32_bf16(eb0, xb0, d, 0, 0, 0);
      d = __builtin_amdgcn_mfma_f32_16x16x32_bf16(eb1, xb1, d, 0, 0, 0);
      const float4 eq = *(const float4*)(esqp + t * 16 + kg * 4);
      const float s0 = 2.f * d[0] - eq.x;
      const float s1 = 2.f * d[1] - eq.y;
      const float s2 = 2.f * d[2] - eq.z;
      const float s3 = 2.f * d[3] - eq.w;
      float4v lpv = { s0 - lse, s1 - lse, s2 - lse, s3 - lse };
      lp4[t * 4] = lpv;
      const float4 uu = (th == 0) ? cu0 : cu1;
      const float g0 = -__logf(-__logf(uu.x));
      const float g1 = -__logf(-__logf(uu.y));
      const float g2 = -__logf(-__logf(uu.z));
      const float g3 = -__logf(-__logf(uu.w));
      const float y0 = __expf((s0 + g0) * invtau) * rz2;
      const float y1 = __expf((s1 + g1) * invtau) * rz2;
      const float y2 = __expf((s2 + g2) * invtau) * rz2;
      const float y3 = __expf((s3 + g3) * invtau) * rz2;
      sampw[(th * 16 + kg * 4 + 0) * 16 + l15] = f2bf(y0);
      sampw[(th * 16 + kg * 4 + 1) * 16 + l15] = f2bf(y1);
      sampw[(th * 16 + kg * 4 + 2) * 16 + l15] = f2bf(y2);
      sampw[(th * 16 + kg * 4 + 3) * 16 + l15] = f2bf(y3);
    }
    PHASE_B_TAIL(c)
  }

  {
    const size_t qb = (size_t)(b0 + w * 16 + kg * 4) * 512 + n * 64 + l15;
#pragma unroll
    for (int j = 0; j < 4; ++j) {
      gq[qb + (size_t)j * 512 +  0] = qacc0[j];
      gq[qb + (size_t)j * 512 + 16] = qacc1[j];
      gq[qb + (size_t)j * 512 + 32] = qacc2[j];
      gq[qb + (size_t)j * 512 + 48] = qacc3[j];
    }
  }

  klrow += __shfl_xor(klrow, 1); klrow += __shfl_xor(klrow, 2);
  klrow += __shfl_xor(klrow, 4); klrow += __shfl_xor(klrow, 8);

  __syncthreads();
  float* avgl = (float*)(smem + R2);
  float* kls  = (float*)smem;
  if (lane == 0) kls[w] = klrow;
  *(float4v*)(avgl + w * 512 + l15 * 32 + kg * 4)      = avgA;
  *(float4v*)(avgl + w * 512 + l15 * 32 + 16 + kg * 4) = avgB;
  __syncthreads();
  {
    float s = 0.f;
#pragma unroll
    for (int ww = 0; ww < 8; ++ww) s += avgl[ww * 512 + tid];
    ws_avg[(size_t)blockIdx.x * 512 + tid] = s;
    if (tid == 0) {
      float k = 0.f;
#pragma unroll
      for (int i = 0; i < 8; ++i) k += kls[i];
      ws_kl[blockIdx.x] = k;
    }
  }
}

extern "C" __global__ void __launch_bounds__(512)
vq_fin(const float* __restrict__ ws_avg, const float* __restrict__ ws_kl,
       float* __restrict__ scal)
{
  __shared__ float red[8];
  const int tid = threadIdx.x, lane = tid & 63, w = tid >> 6;
  float pps = 0.f;
  for (int n = 0; n < 8; ++n) {
    float s = 0.f;
    for (int bt = 0; bt < 64; ++bt) s += ws_avg[(size_t)(n * 64 + bt) * 512 + tid];
    const float avg = s * (1.0f / 8192.0f);
    float term = avg * __logf(avg + 1e-10f);
#pragma unroll
    for (int o = 1; o < 64; o <<= 1) term += __shfl_xor(term, o);
    __syncthreads();
    if (lane == 0) red[w] = term;
    __syncthreads();
    if (tid == 0) {
      float tt = 0.f;
#pragma unroll
      for (int i = 0; i < 8; ++i) tt += red[i];
      pps += __expf(-tt);
    }
  }
  float kv = ws_kl[tid];
#pragma unroll
  for (int o = 1; o < 64; o <<= 1) kv += __shfl_xor(kv, o);
  __syncthreads();
  if (lane == 0) red[w] = kv;
  __syncthreads();
  if (tid == 0) {
    float k = 0.f;
#pragma unroll
    for (int i = 0; i < 8; ++i) k += red[i];
    scal[0] = k * (1.0f / 8192.0f);
    scal[1] = pps;
  }
}

extern "C" void kernel_launch(void* const* d_in, const int* in_sizes, int n_in,
                              void* d_out, int out_size, void* d_ws, size_t ws_size,
                              hipStream_t stream)
{
  const float* gx = (const float*)d_in[0];
  const float* ge = (const float*)d_in[1];
  const float* gu = (const float*)d_in[2];
  const float* gt = (const float*)d_in[3];
  float* out  = (float*)d_out;
  float* gq   = out;
  float* scal = out + 4194304;
  float* glg  = out + 4194306;

  // fast path needs: gy 64MB + ws_avg 1MB + ws_kl 2KB
  const size_t GY_BYTES = (size_t)512 * 8 * 2048 * 8;          // 64 MiB
  const size_t NEED = GY_BYTES + (size_t)512 * 512 * 4 + 2048;

  if (ws_size >= NEED) {
    ull*   gy     = (ull*)d_ws;
    float* ws_avg = (float*)((char*)d_ws + GY_BYTES);
    float* ws_kl  = ws_avg + 512 * 512;
    (void)hipFuncSetAttribute((const void*)vq_main_ws,
                              hipFuncAttributeMaxDynamicSharedMemorySize, LDS_FAST);
    vq_main_ws<<<dim3(512), dim3(512), LDS_FAST, stream>>>(gx, ge, gu, gt, gq, glg,
                                                           gy, ws_avg, ws_kl);
    vq_fin<<<dim3(1), dim3(512), 0, stream>>>(ws_avg, ws_kl, scal);
  } else {
    float* ws_avg = (float*)d_ws;
    float* ws_kl  = ws_avg + 512 * 512;
    (void)hipFuncSetAttribute((const void*)vq_main_fb,
                              hipFuncAttributeMaxDynamicSharedMemorySize, LDS_SZ);
    vq_main_fb<<<dim3(512), dim3(512), LDS_SZ, stream>>>(gx, ge, gu, gt, gq, glg,
                                                         ws_avg, ws_kl);
    vq_fin<<<dim3(1), dim3(512), 0, stream>>>(ws_avg, ws_kl, scal);
  }
}

// Round 10
// 263.386 us; speedup vs baseline: 1.4575x; 1.4575x over previous
//
#include <hip/hip_runtime.h>
#include <stdint.h>

typedef short short8 __attribute__((ext_vector_type(8)));
typedef float float4v __attribute__((ext_vector_type(4)));
typedef unsigned long long ull;

// Sizes fixed: N=8, M=512, D=64, B=8192. Block: one n, 128 b-rows, 8 waves.
// mfma(E, X): C rows = m-local (kg*4+j), cols = b (l15).
// ROUND 10 = round-6 champion + 8-deep u prefetch (both sweeps) + nontemporal
// lp/gq stores. No structural changes.
//
// LDS map (80 KB -> 2 blocks/CU):
//   [0, 65536)      E bf16 [512 m][128 B], XOR-swizzled rows (byte ^= (m&7)<<4)
//   [65536, 81920)  region2, time-multiplexed:
//     stage:   X bf16 [128 r][128 B] swizzled
//     sweeps:  esq f32 [512]          @ +0
//     sweep2:  samp chunks 8 x 1 KB   @ +8192  ([32 m][16 r] bf16, 32B rows)
//     finale:  avg f32 [8][512]       @ +0     (after bar4; kls in dead E region)
#define R2      65536
#define LDS_SZ  81920

__device__ __forceinline__ unsigned cvtpk(float a, float b){
  unsigned d;
  asm("v_cvt_pk_bf16_f32 %0, %1, %2" : "=v"(d) : "v"(a), "v"(b));
  return d;
}
__device__ __forceinline__ unsigned short f2bf(float f){
  unsigned u = __float_as_uint(f);
  return (unsigned short)((u + 0x7FFFu + ((u >> 16) & 1u)) >> 16);
}

template<int OFF>
__device__ __forceinline__ ull tr16(unsigned a){
  ull d;
  asm volatile("ds_read_b64_tr_b16 %0, %1 offset:%c2" : "=v"(d) : "v"(a), "i"(OFF));
  return d;
}
__device__ __forceinline__ short8 mk8(ull lo, ull hi){
  union { ull q[2]; short8 v; } u; u.q[0] = lo; u.q[1] = hi; return u.v;
}

extern "C" __global__ void __launch_bounds__(512, 4)
vq_main(const float* __restrict__ gx, const float* __restrict__ ge,
        const float* __restrict__ gu, const float* __restrict__ gtau,
        float* __restrict__ gq, float* __restrict__ glg,
        float* __restrict__ ws_avg, float* __restrict__ ws_kl)
{
  extern __shared__ char smem[];
  const int tid = threadIdx.x;
  const int n   = blockIdx.x >> 6;
  const int b0  = (blockIdx.x & 63) * 128;

  // ---- stage embedding -> bf16 LDS (swizzled); esq kept in a register ----
  float esq_reg = 0.f;
  {
    const int m = tid;
    const float* src = ge + (size_t)(n * 512 + m) * 64;
    char* dst = smem + m * 128;
    const unsigned sw = (unsigned)((m & 7) << 4);
#pragma unroll
    for (int c = 0; c < 8; ++c) {
      float4 a = *(const float4*)(src + c * 8);
      float4 b = *(const float4*)(src + c * 8 + 4);
      esq_reg += a.x*a.x + a.y*a.y + a.z*a.z + a.w*a.w
               + b.x*b.x + b.y*b.y + b.z*b.z + b.w*b.w;
      uint4 v = { cvtpk(a.x, a.y), cvtpk(a.z, a.w), cvtpk(b.x, b.y), cvtpk(b.z, b.w) };
      *(uint4*)(dst + (((unsigned)(c * 16)) ^ sw)) = v;
    }
  }
  // ---- stage x tile -> bf16 LDS rows (swizzled) in region2 ----
  {
    const int r = tid >> 2, qq = tid & 3;
    const float* src = gx + (size_t)(b0 + r) * 512 + n * 64 + qq * 16;
    char* dst = smem + R2 + r * 128;
    const unsigned sw = (unsigned)((r & 7) << 4);
#pragma unroll
    for (int h = 0; h < 2; ++h) {
      float4 a = *(const float4*)(src + h * 8);
      float4 b = *(const float4*)(src + h * 8 + 4);
      uint4 v = { cvtpk(a.x, a.y), cvtpk(a.z, a.w), cvtpk(b.x, b.y), cvtpk(b.z, b.w) };
      *(uint4*)(dst + (((unsigned)((qq * 2 + h) * 16)) ^ sw)) = v;
    }
  }
  __syncthreads();                                    // bar1

  const int lane = tid & 63;
  const int w    = tid >> 6;
  const int l15  = lane & 15;
  const int kg   = lane >> 4;
  const unsigned swl = (unsigned)((l15 & 7) << 4);

  // ---- X B-fragments (col = b-row = w*16+l15) ----
  const char* xrow = smem + R2 + (w * 16 + l15) * 128;
  const short8 xb0 = *(const short8*)(xrow + (((unsigned)(kg * 16)) ^ swl));
  const short8 xb1 = *(const short8*)(xrow + (((unsigned)(64 + kg * 16)) ^ swl));
  __syncthreads();                                    // bar2: X region free
  ((float*)(smem + R2))[tid] = esq_reg;               // esq[512] @ R2
  __syncthreads();                                    // bar3

  const char* erow = smem + l15 * 128;
  const unsigned eo0 = ((unsigned)(kg * 16)) ^ swl;
  const unsigned eo1 = ((unsigned)(64 + kg * 16)) ^ swl;
  const float* esqp = (const float*)(smem + R2);

  const float invtau = 1.0f / gtau[0];
  const float4* up4 = (const float4*)(gu + (size_t)n * 4194304
                     + (size_t)(b0 + w * 16 + l15) * 512 + kg * 4);

  // ---- sweep 1: Z, Wk, and Z2' = sum(exp((s+g)/tau)) (lse-free shift) ----
  // 8-deep u prefetch: 8 outstanding dwordx4 per lane.
  float Z = 0.f, Wk = 0.f, Z2 = 0.f;
  {
    float4 P[8];
#pragma unroll
    for (int i = 0; i < 8; ++i) P[i] = up4[i * 4];
#pragma unroll
    for (int t = 0; t < 32; ++t) {
      short8 eb0 = *(const short8*)(erow + t * 2048 + eo0);
      short8 eb1 = *(const short8*)(erow + t * 2048 + eo1);
      float4v d = (float4v){0.f, 0.f, 0.f, 0.f};
      d = __builtin_amdgcn_mfma_f32_16x16x32_bf16(eb0, xb0, d, 0, 0, 0);
      d = __builtin_amdgcn_mfma_f32_16x16x32_bf16(eb1, xb1, d, 0, 0, 0);
      const float4 eq = *(const float4*)(esqp + t * 16 + kg * 4);
      const float s0 = 2.f * d[0] - eq.x;
      const float s1 = 2.f * d[1] - eq.y;
      const float s2 = 2.f * d[2] - eq.z;
      const float s3 = 2.f * d[3] - eq.w;
      const float e0 = __expf(s0), e1 = __expf(s1), e2 = __expf(s2), e3 = __expf(s3);
      Z  += (e0 + e1) + (e2 + e3);
      Wk += e0 * s0 + e1 * s1 + e2 * s2 + e3 * s3;
      const float4 uu = P[t & 7];
      if (t < 24) P[t & 7] = up4[(t + 8) * 4];
      const float g0 = -__logf(-__logf(uu.x));
      const float g1 = -__logf(-__logf(uu.y));
      const float g2 = -__logf(-__logf(uu.z));
      const float g3 = -__logf(-__logf(uu.w));
      Z2 += __expf((s0 + g0) * invtau) + __expf((s1 + g1) * invtau)
          + __expf((s2 + g2) * invtau) + __expf((s3 + g3) * invtau);
    }
  }
  Z  += __shfl_xor(Z, 16);  Z  += __shfl_xor(Z, 32);
  Wk += __shfl_xor(Wk, 16); Wk += __shfl_xor(Wk, 32);
  Z2 += __shfl_xor(Z2, 16); Z2 += __shfl_xor(Z2, 32);
  const float lse = __logf(Z);
  const float logM = 6.2383246250395075f;
  float klrow = Wk * __builtin_amdgcn_rcpf(Z) - lse + logM;  // row KL (dup x4 over kg)
  const float rz2 = __builtin_amdgcn_rcpf(Z2);

  // ---- sweep 2 fused with quantize: recompute s,g; lp -> glg; y*rz2 -> LDS ----
  float4v* lp4 = (float4v*)(glg + (size_t)(b0 + w * 16 + l15) * 4096 + n * 512 + kg * 4);
  ushort* sampw = (ushort*)(smem + R2 + 8192 + w * 1024);   // [32 m][16 r]
  const char* sampc = (const char*)sampw;
  const unsigned trA = (unsigned)(uintptr_t)sampw
                     + (unsigned)(kg * 128 + (l15 >> 2) * 32 + (l15 & 3) * 8);
  const int mrow = kg * 4 + (l15 >> 2);
  const unsigned ebase = (unsigned)(uintptr_t)smem + (unsigned)(mrow * 128);
  const unsigned msw = ((unsigned)(mrow & 7)) << 4;
  unsigned trB0 = ebase + ((unsigned)(  0 + (l15 & 3) * 8) ^ msw);
  unsigned trB1 = ebase + ((unsigned)( 32 + (l15 & 3) * 8) ^ msw);
  unsigned trB2 = ebase + ((unsigned)( 64 + (l15 & 3) * 8) ^ msw);
  unsigned trB3 = ebase + ((unsigned)( 96 + (l15 & 3) * 8) ^ msw);

  float4v qacc0 = (float4v){0.f,0.f,0.f,0.f};
  float4v qacc1 = (float4v){0.f,0.f,0.f,0.f};
  float4v qacc2 = (float4v){0.f,0.f,0.f,0.f};
  float4v qacc3 = (float4v){0.f,0.f,0.f,0.f};
  float4v avgA  = (float4v){0.f,0.f,0.f,0.f};
  float4v avgB  = (float4v){0.f,0.f,0.f,0.f};

  {
    float4 P[8];
#pragma unroll
    for (int i = 0; i < 8; ++i) P[i] = up4[i * 4];
#pragma unroll
    for (int c = 0; c < 16; ++c) {
#pragma unroll
      for (int th = 0; th < 2; ++th) {
        const int t = c * 2 + th;
        short8 eb0 = *(const short8*)(erow + t * 2048 + eo0);
        short8 eb1 = *(const short8*)(erow + t * 2048 + eo1);
        float4v d = (float4v){0.f, 0.f, 0.f, 0.f};
        d = __builtin_amdgcn_mfma_f32_16x16x32_bf16(eb0, xb0, d, 0, 0, 0);
        d = __builtin_amdgcn_mfma_f32_16x16x32_bf16(eb1, xb1, d, 0, 0, 0);
        const float4 eq = *(const float4*)(esqp + t * 16 + kg * 4);
        const float s0 = 2.f * d[0] - eq.x;
        const float s1 = 2.f * d[1] - eq.y;
        const float s2 = 2.f * d[2] - eq.z;
        const float s3 = 2.f * d[3] - eq.w;
        float4v lpv = { s0 - lse, s1 - lse, s2 - lse, s3 - lse };
        __builtin_nontemporal_store(lpv, lp4 + t * 4);
        const float4 uu = P[t & 7];
        if (t < 24) P[t & 7] = up4[(t + 8) * 4];
        const float g0 = -__logf(-__logf(uu.x));
        const float g1 = -__logf(-__logf(uu.y));
        const float g2 = -__logf(-__logf(uu.z));
        const float g3 = -__logf(-__logf(uu.w));
        const float y0 = __expf((s0 + g0) * invtau) * rz2;
        const float y1 = __expf((s1 + g1) * invtau) * rz2;
        const float y2 = __expf((s2 + g2) * invtau) * rz2;
        const float y3 = __expf((s3 + g3) * invtau) * rz2;
        sampw[(th * 16 + kg * 4 + 0) * 16 + l15] = f2bf(y0);
        sampw[(th * 16 + kg * 4 + 1) * 16 + l15] = f2bf(y1);
        sampw[(th * 16 + kg * 4 + 2) * 16 + l15] = f2bf(y2);
        sampw[(th * 16 + kg * 4 + 3) * 16 + l15] = f2bf(y3);
      }
      asm volatile("s_waitcnt lgkmcnt(0)" ::: "memory");
      __builtin_amdgcn_sched_barrier(0);
      const short8 avA = *(const short8*)(sampc + l15 * 32 + (kg & 1) * 16);
      const short8 avB = *(const short8*)(sampc + 512 + l15 * 32 + (kg & 1) * 16);
      ull alo = tr16<0>(trA),  ahi = tr16<512>(trA);
      ull b0l = tr16<0>(trB0), b0h = tr16<2048>(trB0);
      ull b1l = tr16<0>(trB1), b1h = tr16<2048>(trB1);
      ull b2l = tr16<0>(trB2), b2h = tr16<2048>(trB2);
      ull b3l = tr16<0>(trB3), b3h = tr16<2048>(trB3);
      asm volatile("s_waitcnt lgkmcnt(0)" ::: "memory");
      __builtin_amdgcn_sched_barrier(0);
      const unsigned onv = ((l15 == c) && (kg < 2)) ? 0x3F803F80u : 0u;
      union { unsigned u[4]; short8 v; } bs;
      bs.u[0] = onv; bs.u[1] = onv; bs.u[2] = onv; bs.u[3] = onv;
      short8 aa = mk8(alo, ahi);
      qacc0 = __builtin_amdgcn_mfma_f32_16x16x32_bf16(aa, mk8(b0l, b0h), qacc0, 0, 0, 0);
      qacc1 = __builtin_amdgcn_mfma_f32_16x16x32_bf16(aa, mk8(b1l, b1h), qacc1, 0, 0, 0);
      qacc2 = __builtin_amdgcn_mfma_f32_16x16x32_bf16(aa, mk8(b2l, b2h), qacc2, 0, 0, 0);
      qacc3 = __builtin_amdgcn_mfma_f32_16x16x32_bf16(aa, mk8(b3l, b3h), qacc3, 0, 0, 0);
      avgA  = __builtin_amdgcn_mfma_f32_16x16x32_bf16(avA, bs.v, avgA, 0, 0, 0);
      avgB  = __builtin_amdgcn_mfma_f32_16x16x32_bf16(avB, bs.v, avgB, 0, 0, 0);
      trB0 += 4096; trB1 += 4096; trB2 += 4096; trB3 += 4096;
    }
  }

  // ---- store quantized (row b = kg*4+j, col d = l15) ----
  {
    const size_t qb = (size_t)(b0 + w * 16 + kg * 4) * 512 + n * 64 + l15;
#pragma unroll
    for (int j = 0; j < 4; ++j) {
      __builtin_nontemporal_store(qacc0[j], gq + qb + (size_t)j * 512 +  0);
      __builtin_nontemporal_store(qacc1[j], gq + qb + (size_t)j * 512 + 16);
      __builtin_nontemporal_store(qacc2[j], gq + qb + (size_t)j * 512 + 32);
      __builtin_nontemporal_store(qacc3[j], gq + qb + (size_t)j * 512 + 48);
    }
  }

  // ---- KL full-wave value (rows = l15; dup over kg collapses, not sums) ----
  klrow += __shfl_xor(klrow, 1); klrow += __shfl_xor(klrow, 2);
  klrow += __shfl_xor(klrow, 4); klrow += __shfl_xor(klrow, 8);

  __syncthreads();                                    // bar4: samp + esq + E dead
  float* avgl = (float*)(smem + R2);                  // [8][512]
  float* kls  = (float*)smem;                         // in dead E region
  if (lane == 0) kls[w] = klrow;
  // avgA[j]: m = l15*32 + kg*4 + j ; avgB[j]: m = l15*32 + 16 + kg*4 + j
  *(float4v*)(avgl + w * 512 + l15 * 32 + kg * 4)      = avgA;
  *(float4v*)(avgl + w * 512 + l15 * 32 + 16 + kg * 4) = avgB;
  __syncthreads();                                    // bar5
  {
    float s = 0.f;
#pragma unroll
    for (int ww = 0; ww < 8; ++ww) s += avgl[ww * 512 + tid];
    ws_avg[(size_t)blockIdx.x * 512 + tid] = s;
    if (tid == 0) {
      float k = 0.f;
#pragma unroll
      for (int i = 0; i < 8; ++i) k += kls[i];
      ws_kl[blockIdx.x] = k;
    }
  }
}

extern "C" __global__ void __launch_bounds__(512)
vq_fin(const float* __restrict__ ws_avg, const float* __restrict__ ws_kl,
       float* __restrict__ scal)
{
  __shared__ float red[8];
  const int tid = threadIdx.x, lane = tid & 63, w = tid >> 6;
  float pps = 0.f;
  for (int n = 0; n < 8; ++n) {
    float s = 0.f;
    for (int bt = 0; bt < 64; ++bt) s += ws_avg[(size_t)(n * 64 + bt) * 512 + tid];
    const float avg = s * (1.0f / 8192.0f);
    float term = avg * __logf(avg + 1e-10f);
#pragma unroll
    for (int o = 1; o < 64; o <<= 1) term += __shfl_xor(term, o);
    __syncthreads();
    if (lane == 0) red[w] = term;
    __syncthreads();
    if (tid == 0) {
      float tt = 0.f;
#pragma unroll
      for (int i = 0; i < 8; ++i) tt += red[i];
      pps += __expf(-tt);
    }
  }
  float kv = ws_kl[tid];
#pragma unroll
  for (int o = 1; o < 64; o <<= 1) kv += __shfl_xor(kv, o);
  __syncthreads();
  if (lane == 0) red[w] = kv;
  __syncthreads();
  if (tid == 0) {
    float k = 0.f;
#pragma unroll
    for (int i = 0; i < 8; ++i) k += red[i];
    scal[0] = k * (1.0f / 8192.0f);
    scal[1] = pps;
  }
}

extern "C" void kernel_launch(void* const* d_in, const int* in_sizes, int n_in,
                              void* d_out, int out_size, void* d_ws, size_t ws_size,
                              hipStream_t stream)
{
  const float* gx = (const float*)d_in[0];
  const float* ge = (const float*)d_in[1];
  const float* gu = (const float*)d_in[2];
  const float* gt = (const float*)d_in[3];
  float* out  = (float*)d_out;
  float* gq   = out;
  float* scal = out + 4194304;
  float* glg  = out + 4194306;
  float* ws_avg = (float*)d_ws;
  float* ws_kl  = ws_avg + 512 * 512;

  (void)hipFuncSetAttribute((const void*)vq_main,
                            hipFuncAttributeMaxDynamicSharedMemorySize, LDS_SZ);
  vq_main<<<dim3(512), dim3(512), LDS_SZ, stream>>>(gx, ge, gu, gt, gq, glg, ws_avg, ws_kl);
  vq_fin<<<dim3(1), dim3(512), 0, stream>>>(ws_avg, ws_kl, scal);
}

// Round 11
// 223.702 us; speedup vs baseline: 1.7160x; 1.1774x over previous
//
#include <hip/hip_runtime.h>
#include <stdint.h>

typedef short short8 __attribute__((ext_vector_type(8)));
typedef float float4v __attribute__((ext_vector_type(4)));
typedef unsigned long long ull;

// Sizes fixed: N=8, M=512, D=64, B=8192. Block: one n, 128 b-rows, 8 waves.
// mfma(E, X): C rows = m-local (kg*4+j), cols = b (l15).
// ROUND 11 = round-6 champion + tau==1 fast path in BOTH sweeps:
//   y_un = e^s * rcp(-ln u)   (== exp(s+g), g = -ln(-ln u), tau=1)
// e^s is already computed for Z, so sweep1 drops exp(s+g) and one log;
// sweep2 drops one log. Identical f32 formulas in both sweeps keep Z2 and y
// consistent. No register-pressure change, no structural change.
//
// LDS map (80 KB -> 2 blocks/CU):
//   [0, 65536)      E bf16 [512 m][128 B], XOR-swizzled rows (byte ^= (m&7)<<4)
//   [65536, 81920)  region2, time-multiplexed:
//     stage:   X bf16 [128 r][128 B] swizzled
//     sweeps:  esq f32 [512]          @ +0
//     sweep2:  samp chunks 8 x 1 KB   @ +8192  ([32 m][16 r] bf16, 32B rows)
//     finale:  avg f32 [8][512]       @ +0     (after bar4; kls in dead E region)
#define R2      65536
#define LDS_SZ  81920

__device__ __forceinline__ unsigned cvtpk(float a, float b){
  unsigned d;
  asm("v_cvt_pk_bf16_f32 %0, %1, %2" : "=v"(d) : "v"(a), "v"(b));
  return d;
}
__device__ __forceinline__ unsigned short f2bf(float f){
  unsigned u = __float_as_uint(f);
  return (unsigned short)((u + 0x7FFFu + ((u >> 16) & 1u)) >> 16);
}

template<int OFF>
__device__ __forceinline__ ull tr16(unsigned a){
  ull d;
  asm volatile("ds_read_b64_tr_b16 %0, %1 offset:%c2" : "=v"(d) : "v"(a), "i"(OFF));
  return d;
}
__device__ __forceinline__ short8 mk8(ull lo, ull hi){
  union { ull q[2]; short8 v; } u; u.q[0] = lo; u.q[1] = hi; return u.v;
}

extern "C" __global__ void __launch_bounds__(512, 4)
vq_main(const float* __restrict__ gx, const float* __restrict__ ge,
        const float* __restrict__ gu, const float* __restrict__ gtau,
        float* __restrict__ gq, float* __restrict__ glg,
        float* __restrict__ ws_avg, float* __restrict__ ws_kl)
{
  extern __shared__ char smem[];
  const int tid = threadIdx.x;
  const int n   = blockIdx.x >> 6;
  const int b0  = (blockIdx.x & 63) * 128;

  // ---- stage embedding -> bf16 LDS (swizzled); esq kept in a register ----
  float esq_reg = 0.f;
  {
    const int m = tid;
    const float* src = ge + (size_t)(n * 512 + m) * 64;
    char* dst = smem + m * 128;
    const unsigned sw = (unsigned)((m & 7) << 4);
#pragma unroll
    for (int c = 0; c < 8; ++c) {
      float4 a = *(const float4*)(src + c * 8);
      float4 b = *(const float4*)(src + c * 8 + 4);
      esq_reg += a.x*a.x + a.y*a.y + a.z*a.z + a.w*a.w
               + b.x*b.x + b.y*b.y + b.z*b.z + b.w*b.w;
      uint4 v = { cvtpk(a.x, a.y), cvtpk(a.z, a.w), cvtpk(b.x, b.y), cvtpk(b.z, b.w) };
      *(uint4*)(dst + (((unsigned)(c * 16)) ^ sw)) = v;
    }
  }
  // ---- stage x tile -> bf16 LDS rows (swizzled) in region2 ----
  {
    const int r = tid >> 2, qq = tid & 3;
    const float* src = gx + (size_t)(b0 + r) * 512 + n * 64 + qq * 16;
    char* dst = smem + R2 + r * 128;
    const unsigned sw = (unsigned)((r & 7) << 4);
#pragma unroll
    for (int h = 0; h < 2; ++h) {
      float4 a = *(const float4*)(src + h * 8);
      float4 b = *(const float4*)(src + h * 8 + 4);
      uint4 v = { cvtpk(a.x, a.y), cvtpk(a.z, a.w), cvtpk(b.x, b.y), cvtpk(b.z, b.w) };
      *(uint4*)(dst + (((unsigned)((qq * 2 + h) * 16)) ^ sw)) = v;
    }
  }
  __syncthreads();                                    // bar1

  const int lane = tid & 63;
  const int w    = tid >> 6;
  const int l15  = lane & 15;
  const int kg   = lane >> 4;
  const unsigned swl = (unsigned)((l15 & 7) << 4);

  // ---- X B-fragments (col = b-row = w*16+l15) ----
  const char* xrow = smem + R2 + (w * 16 + l15) * 128;
  const short8 xb0 = *(const short8*)(xrow + (((unsigned)(kg * 16)) ^ swl));
  const short8 xb1 = *(const short8*)(xrow + (((unsigned)(64 + kg * 16)) ^ swl));
  __syncthreads();                                    // bar2: X region free
  ((float*)(smem + R2))[tid] = esq_reg;               // esq[512] @ R2
  __syncthreads();                                    // bar3

  const char* erow = smem + l15 * 128;
  const unsigned eo0 = ((unsigned)(kg * 16)) ^ swl;
  const unsigned eo1 = ((unsigned)(64 + kg * 16)) ^ swl;
  const float* esqp = (const float*)(smem + R2);

  const float tauv = gtau[0];
  const bool tau1 = (tauv == 1.0f);
  const float invtau = 1.0f / tauv;
  const float4* up4 = (const float4*)(gu + (size_t)n * 4194304
                     + (size_t)(b0 + w * 16 + l15) * 512 + kg * 4);

  // ---- sweep 1: Z, Wk, Z2' = sum y_un  (lse-free shift invariance) ----
  float Z = 0.f, Wk = 0.f, Z2 = 0.f;

#define SWEEP1(YE0, YE1, YE2, YE3)                                             \
  {                                                                            \
    float4 Pa = up4[0], Pb = up4[4], Pc = up4[8], Pd = up4[12];                \
    _Pragma("unroll")                                                          \
    for (int t = 0; t < 32; ++t) {                                             \
      short8 eb0 = *(const short8*)(erow + t * 2048 + eo0);                    \
      short8 eb1 = *(const short8*)(erow + t * 2048 + eo1);                    \
      float4v d = (float4v){0.f, 0.f, 0.f, 0.f};                               \
      d = __builtin_amdgcn_mfma_f32_16x16x32_bf16(eb0, xb0, d, 0, 0, 0);       \
      d = __builtin_amdgcn_mfma_f32_16x16x32_bf16(eb1, xb1, d, 0, 0, 0);       \
      const float4 eq = *(const float4*)(esqp + t * 16 + kg * 4);              \
      const float s0 = 2.f * d[0] - eq.x;                                      \
      const float s1 = 2.f * d[1] - eq.y;                                      \
      const float s2 = 2.f * d[2] - eq.z;                                      \
      const float s3 = 2.f * d[3] - eq.w;                                      \
      const float e0 = __expf(s0), e1 = __expf(s1);                            \
      const float e2 = __expf(s2), e3 = __expf(s3);                            \
      Z  += (e0 + e1) + (e2 + e3);                                             \
      Wk += e0 * s0 + e1 * s1 + e2 * s2 + e3 * s3;                             \
      const float4 uu = Pa;                                                    \
      Pa = Pb; Pb = Pc; Pc = Pd;                                               \
      if (t < 28) Pd = up4[(t + 4) * 4];                                       \
      const float l0 = -__logf(uu.x), l1 = -__logf(uu.y);                      \
      const float l2 = -__logf(uu.z), l3 = -__logf(uu.w);                      \
      Z2 += (YE0) + (YE1) + (YE2) + (YE3);                                     \
    }                                                                          \
  }

  if (tau1) {
    SWEEP1(e0 * __builtin_amdgcn_rcpf(l0), e1 * __builtin_amdgcn_rcpf(l1),
           e2 * __builtin_amdgcn_rcpf(l2), e3 * __builtin_amdgcn_rcpf(l3))
  } else {
    SWEEP1(__expf((s0 - __logf(l0)) * invtau), __expf((s1 - __logf(l1)) * invtau),
           __expf((s2 - __logf(l2)) * invtau), __expf((s3 - __logf(l3)) * invtau))
  }
#undef SWEEP1

  Z  += __shfl_xor(Z, 16);  Z  += __shfl_xor(Z, 32);
  Wk += __shfl_xor(Wk, 16); Wk += __shfl_xor(Wk, 32);
  Z2 += __shfl_xor(Z2, 16); Z2 += __shfl_xor(Z2, 32);
  const float lse = __logf(Z);
  const float logM = 6.2383246250395075f;
  float klrow = Wk * __builtin_amdgcn_rcpf(Z) - lse + logM;  // row KL (dup x4 over kg)
  const float rz2 = __builtin_amdgcn_rcpf(Z2);

  // ---- sweep 2 fused with quantize: recompute s (+ same y formula) ----
  float4v* lp4 = (float4v*)(glg + (size_t)(b0 + w * 16 + l15) * 4096 + n * 512 + kg * 4);
  ushort* sampw = (ushort*)(smem + R2 + 8192 + w * 1024);   // [32 m][16 r]
  const char* sampc = (const char*)sampw;
  const unsigned trA = (unsigned)(uintptr_t)sampw
                     + (unsigned)(kg * 128 + (l15 >> 2) * 32 + (l15 & 3) * 8);
  const int mrow = kg * 4 + (l15 >> 2);
  const unsigned ebase = (unsigned)(uintptr_t)smem + (unsigned)(mrow * 128);
  const unsigned msw = ((unsigned)(mrow & 7)) << 4;
  unsigned trB0 = ebase + ((unsigned)(  0 + (l15 & 3) * 8) ^ msw);
  unsigned trB1 = ebase + ((unsigned)( 32 + (l15 & 3) * 8) ^ msw);
  unsigned trB2 = ebase + ((unsigned)( 64 + (l15 & 3) * 8) ^ msw);
  unsigned trB3 = ebase + ((unsigned)( 96 + (l15 & 3) * 8) ^ msw);

  float4v qacc0 = (float4v){0.f,0.f,0.f,0.f};
  float4v qacc1 = (float4v){0.f,0.f,0.f,0.f};
  float4v qacc2 = (float4v){0.f,0.f,0.f,0.f};
  float4v qacc3 = (float4v){0.f,0.f,0.f,0.f};
  float4v avgA  = (float4v){0.f,0.f,0.f,0.f};
  float4v avgB  = (float4v){0.f,0.f,0.f,0.f};

#define SWEEP2(YF0, YF1, YF2, YF3)                                             \
  {                                                                            \
    float4 P0 = up4[0], P1 = up4[4], P2 = up4[8], P3 = up4[12];                \
    _Pragma("unroll")                                                          \
    for (int c = 0; c < 16; ++c) {                                             \
      const float4 cu0 = P0, cu1 = P1;                                         \
      P0 = P2; P1 = P3;                                                        \
      if (c < 14) { P2 = up4[(2 * c + 4) * 4]; P3 = up4[(2 * c + 5) * 4]; }    \
      _Pragma("unroll")                                                        \
      for (int th = 0; th < 2; ++th) {                                         \
        const int t = c * 2 + th;                                              \
        short8 eb0 = *(const short8*)(erow + t * 2048 + eo0);                  \
        short8 eb1 = *(const short8*)(erow + t * 2048 + eo1);                  \
        float4v d = (float4v){0.f, 0.f, 0.f, 0.f};                             \
        d = __builtin_amdgcn_mfma_f32_16x16x32_bf16(eb0, xb0, d, 0, 0, 0);     \
        d = __builtin_amdgcn_mfma_f32_16x16x32_bf16(eb1, xb1, d, 0, 0, 0);     \
        const float4 eq = *(const float4*)(esqp + t * 16 + kg * 4);            \
        const float s0 = 2.f * d[0] - eq.x;                                    \
        const float s1 = 2.f * d[1] - eq.y;                                    \
        const float s2 = 2.f * d[2] - eq.z;                                    \
        const float s3 = 2.f * d[3] - eq.w;                                    \
        float4v lpv = { s0 - lse, s1 - lse, s2 - lse, s3 - lse };              \
        lp4[t * 4] = lpv;                                                      \
        const float4 uu = (th == 0) ? cu0 : cu1;                               \
        const float l0 = -__logf(uu.x), l1 = -__logf(uu.y);                    \
        const float l2 = -__logf(uu.z), l3 = -__logf(uu.w);                    \
        const float y0 = (YF0) * rz2;                                          \
        const float y1 = (YF1) * rz2;                                          \
        const float y2 = (YF2) * rz2;                                          \
        const float y3 = (YF3) * rz2;                                          \
        sampw[(th * 16 + kg * 4 + 0) * 16 + l15] = f2bf(y0);                   \
        sampw[(th * 16 + kg * 4 + 1) * 16 + l15] = f2bf(y1);                   \
        sampw[(th * 16 + kg * 4 + 2) * 16 + l15] = f2bf(y2);                   \
        sampw[(th * 16 + kg * 4 + 3) * 16 + l15] = f2bf(y3);                   \
      }                                                                        \
      asm volatile("s_waitcnt lgkmcnt(0)" ::: "memory");                       \
      __builtin_amdgcn_sched_barrier(0);                                       \
      const short8 avA = *(const short8*)(sampc + l15 * 32 + (kg & 1) * 16);   \
      const short8 avB = *(const short8*)(sampc + 512 + l15 * 32 + (kg & 1) * 16); \
      ull alo = tr16<0>(trA),  ahi = tr16<512>(trA);                           \
      ull b0l = tr16<0>(trB0), b0h = tr16<2048>(trB0);                         \
      ull b1l = tr16<0>(trB1), b1h = tr16<2048>(trB1);                         \
      ull b2l = tr16<0>(trB2), b2h = tr16<2048>(trB2);                         \
      ull b3l = tr16<0>(trB3), b3h = tr16<2048>(trB3);                         \
      asm volatile("s_waitcnt lgkmcnt(0)" ::: "memory");                       \
      __builtin_amdgcn_sched_barrier(0);                                       \
      const unsigned onv = ((l15 == c) && (kg < 2)) ? 0x3F803F80u : 0u;        \
      union { unsigned u[4]; short8 v; } bs;                                   \
      bs.u[0] = onv; bs.u[1] = onv; bs.u[2] = onv; bs.u[3] = onv;              \
      short8 aa = mk8(alo, ahi);                                               \
      qacc0 = __builtin_amdgcn_mfma_f32_16x16x32_bf16(aa, mk8(b0l, b0h), qacc0, 0, 0, 0); \
      qacc1 = __builtin_amdgcn_mfma_f32_16x16x32_bf16(aa, mk8(b1l, b1h), qacc1, 0, 0, 0); \
      qacc2 = __builtin_amdgcn_mfma_f32_16x16x32_bf16(aa, mk8(b2l, b2h), qacc2, 0, 0, 0); \
      qacc3 = __builtin_amdgcn_mfma_f32_16x16x32_bf16(aa, mk8(b3l, b3h), qacc3, 0, 0, 0); \
      avgA  = __builtin_amdgcn_mfma_f32_16x16x32_bf16(avA, bs.v, avgA, 0, 0, 0); \
      avgB  = __builtin_amdgcn_mfma_f32_16x16x32_bf16(avB, bs.v, avgB, 0, 0, 0); \
      trB0 += 4096; trB1 += 4096; trB2 += 4096; trB3 += 4096;                  \
    }                                                                          \
  }

  if (tau1) {
    SWEEP2(__expf(s0) * __builtin_amdgcn_rcpf(l0),
           __expf(s1) * __builtin_amdgcn_rcpf(l1),
           __expf(s2) * __builtin_amdgcn_rcpf(l2),
           __expf(s3) * __builtin_amdgcn_rcpf(l3))
  } else {
    SWEEP2(__expf((s0 - __logf(l0)) * invtau), __expf((s1 - __logf(l1)) * invtau),
           __expf((s2 - __logf(l2)) * invtau), __expf((s3 - __logf(l3)) * invtau))
  }
#undef SWEEP2

  // ---- store quantized (row b = kg*4+j, col d = l15) ----
  {
    const size_t qb = (size_t)(b0 + w * 16 + kg * 4) * 512 + n * 64 + l15;
#pragma unroll
    for (int j = 0; j < 4; ++j) {
      gq[qb + (size_t)j * 512 +  0] = qacc0[j];
      gq[qb + (size_t)j * 512 + 16] = qacc1[j];
      gq[qb + (size_t)j * 512 + 32] = qacc2[j];
      gq[qb + (size_t)j * 512 + 48] = qacc3[j];
    }
  }

  // ---- KL full-wave value (rows = l15; dup over kg collapses, not sums) ----
  klrow += __shfl_xor(klrow, 1); klrow += __shfl_xor(klrow, 2);
  klrow += __shfl_xor(klrow, 4); klrow += __shfl_xor(klrow, 8);

  __syncthreads();                                    // bar4: samp + esq + E dead
  float* avgl = (float*)(smem + R2);                  // [8][512]
  float* kls  = (float*)smem;                         // in dead E region
  if (lane == 0) kls[w] = klrow;
  // avgA[j]: m = l15*32 + kg*4 + j ; avgB[j]: m = l15*32 + 16 + kg*4 + j
  *(float4v*)(avgl + w * 512 + l15 * 32 + kg * 4)      = avgA;
  *(float4v*)(avgl + w * 512 + l15 * 32 + 16 + kg * 4) = avgB;
  __syncthreads();                                    // bar5
  {
    float s = 0.f;
#pragma unroll
    for (int ww = 0; ww < 8; ++ww) s += avgl[ww * 512 + tid];
    ws_avg[(size_t)blockIdx.x * 512 + tid] = s;
    if (tid == 0) {
      float k = 0.f;
#pragma unroll
      for (int i = 0; i < 8; ++i) k += kls[i];
      ws_kl[blockIdx.x] = k;
    }
  }
}

extern "C" __global__ void __launch_bounds__(512)
vq_fin(const float* __restrict__ ws_avg, const float* __restrict__ ws_kl,
       float* __restrict__ scal)
{
  __shared__ float red[8];
  const int tid = threadIdx.x, lane = tid & 63, w = tid >> 6;
  float pps = 0.f;
  for (int n = 0; n < 8; ++n) {
    float s = 0.f;
    for (int bt = 0; bt < 64; ++bt) s += ws_avg[(size_t)(n * 64 + bt) * 512 + tid];
    const float avg = s * (1.0f / 8192.0f);
    float term = avg * __logf(avg + 1e-10f);
#pragma unroll
    for (int o = 1; o < 64; o <<= 1) term += __shfl_xor(term, o);
    __syncthreads();
    if (lane == 0) red[w] = term;
    __syncthreads();
    if (tid == 0) {
      float tt = 0.f;
#pragma unroll
      for (int i = 0; i < 8; ++i) tt += red[i];
      pps += __expf(-tt);
    }
  }
  float kv = ws_kl[tid];
#pragma unroll
  for (int o = 1; o < 64; o <<= 1) kv += __shfl_xor(kv, o);
  __syncthreads();
  if (lane == 0) red[w] = kv;
  __syncthreads();
  if (tid == 0) {
    float k = 0.f;
#pragma unroll
    for (int i = 0; i < 8; ++i) k += red[i];
    scal[0] = k * (1.0f / 8192.0f);
    scal[1] = pps;
  }
}

extern "C" void kernel_launch(void* const* d_in, const int* in_sizes, int n_in,
                              void* d_out, int out_size, void* d_ws, size_t ws_size,
                              hipStream_t stream)
{
  const float* gx = (const float*)d_in[0];
  const float* ge = (const float*)d_in[1];
  const float* gu = (const float*)d_in[2];
  const float* gt = (const float*)d_in[3];
  float* out  = (float*)d_out;
  float* gq   = out;
  float* scal = out + 4194304;
  float* glg  = out + 4194306;
  float* ws_avg = (float*)d_ws;
  float* ws_kl  = ws_avg + 512 * 512;

  (void)hipFuncSetAttribute((const void*)vq_main,
                            hipFuncAttributeMaxDynamicSharedMemorySize, LDS_SZ);
  vq_main<<<dim3(512), dim3(512), LDS_SZ, stream>>>(gx, ge, gu, gt, gq, glg, ws_avg, ws_kl);
  vq_fin<<<dim3(1), dim3(512), 0, stream>>>(ws_avg, ws_kl, scal);
}

// Round 12
// 124.178 us; speedup vs baseline: 3.0914x; 1.8015x over previous
//
#include <hip/hip_runtime.h>
#include <stdint.h>

typedef short short8 __attribute__((ext_vector_type(8)));
typedef float float4v __attribute__((ext_vector_type(4)));
typedef unsigned long long ull;

// Sizes fixed: N=8, M=512, D=64, B=8192. Block: one n, 128 b-rows, 8 waves.
// mfma(E, X): C rows = m-local (kg*4+j), cols = b (l15).
// CHAMPION (round 6, 126 us): sweep 1 streams u once computing Z (softmax-1),
// Wk (KL identity), Z2' = sum(exp((s+g)/tau)) via shift-invariance (no lse).
// Sweep 2 recomputes s via MFMA, stores lp, normalizes y*rz2 BEFORE the LDS
// store, then quantize/avg MFMAs consume correctly-normalized samples.
// Occupancy is doubly pinned (LDS 80KB -> 2 blocks/CU; regfile ~118/lane ->
// 16 waves/CU); all perturbations (reg cache, deeper prefetch, LDS diet,
// gy scratch, branch-duplicated tau fast path) spill or are neutral.
//
// LDS map (80 KB -> 2 blocks/CU):
//   [0, 65536)      E bf16 [512 m][128 B], XOR-swizzled rows (byte ^= (m&7)<<4)
//   [65536, 81920)  region2, time-multiplexed:
//     stage:   X bf16 [128 r][128 B] swizzled
//     sweeps:  esq f32 [512]          @ +0
//     sweep2:  samp chunks 8 x 1 KB   @ +8192  ([32 m][16 r] bf16, 32B rows)
//     finale:  avg f32 [8][512]       @ +0     (after bar4; kls in dead E region)
#define R2      65536
#define LDS_SZ  81920

__device__ __forceinline__ unsigned cvtpk(float a, float b){
  unsigned d;
  asm("v_cvt_pk_bf16_f32 %0, %1, %2" : "=v"(d) : "v"(a), "v"(b));
  return d;
}
__device__ __forceinline__ unsigned short f2bf(float f){
  unsigned u = __float_as_uint(f);
  return (unsigned short)((u + 0x7FFFu + ((u >> 16) & 1u)) >> 16);
}

template<int OFF>
__device__ __forceinline__ ull tr16(unsigned a){
  ull d;
  asm volatile("ds_read_b64_tr_b16 %0, %1 offset:%c2" : "=v"(d) : "v"(a), "i"(OFF));
  return d;
}
__device__ __forceinline__ short8 mk8(ull lo, ull hi){
  union { ull q[2]; short8 v; } u; u.q[0] = lo; u.q[1] = hi; return u.v;
}

extern "C" __global__ void __launch_bounds__(512, 4)
vq_main(const float* __restrict__ gx, const float* __restrict__ ge,
        const float* __restrict__ gu, const float* __restrict__ gtau,
        float* __restrict__ gq, float* __restrict__ glg,
        float* __restrict__ ws_avg, float* __restrict__ ws_kl)
{
  extern __shared__ char smem[];
  const int tid = threadIdx.x;
  const int n   = blockIdx.x >> 6;
  const int b0  = (blockIdx.x & 63) * 128;

  // ---- stage embedding -> bf16 LDS (swizzled); esq kept in a register ----
  float esq_reg = 0.f;
  {
    const int m = tid;
    const float* src = ge + (size_t)(n * 512 + m) * 64;
    char* dst = smem + m * 128;
    const unsigned sw = (unsigned)((m & 7) << 4);
#pragma unroll
    for (int c = 0; c < 8; ++c) {
      float4 a = *(const float4*)(src + c * 8);
      float4 b = *(const float4*)(src + c * 8 + 4);
      esq_reg += a.x*a.x + a.y*a.y + a.z*a.z + a.w*a.w
               + b.x*b.x + b.y*b.y + b.z*b.z + b.w*b.w;
      uint4 v = { cvtpk(a.x, a.y), cvtpk(a.z, a.w), cvtpk(b.x, b.y), cvtpk(b.z, b.w) };
      *(uint4*)(dst + (((unsigned)(c * 16)) ^ sw)) = v;
    }
  }
  // ---- stage x tile -> bf16 LDS rows (swizzled) in region2 ----
  {
    const int r = tid >> 2, qq = tid & 3;
    const float* src = gx + (size_t)(b0 + r) * 512 + n * 64 + qq * 16;
    char* dst = smem + R2 + r * 128;
    const unsigned sw = (unsigned)((r & 7) << 4);
#pragma unroll
    for (int h = 0; h < 2; ++h) {
      float4 a = *(const float4*)(src + h * 8);
      float4 b = *(const float4*)(src + h * 8 + 4);
      uint4 v = { cvtpk(a.x, a.y), cvtpk(a.z, a.w), cvtpk(b.x, b.y), cvtpk(b.z, b.w) };
      *(uint4*)(dst + (((unsigned)((qq * 2 + h) * 16)) ^ sw)) = v;
    }
  }
  __syncthreads();                                    // bar1

  const int lane = tid & 63;
  const int w    = tid >> 6;
  const int l15  = lane & 15;
  const int kg   = lane >> 4;
  const unsigned swl = (unsigned)((l15 & 7) << 4);

  // ---- X B-fragments (col = b-row = w*16+l15) ----
  const char* xrow = smem + R2 + (w * 16 + l15) * 128;
  const short8 xb0 = *(const short8*)(xrow + (((unsigned)(kg * 16)) ^ swl));
  const short8 xb1 = *(const short8*)(xrow + (((unsigned)(64 + kg * 16)) ^ swl));
  __syncthreads();                                    // bar2: X region free
  ((float*)(smem + R2))[tid] = esq_reg;               // esq[512] @ R2
  __syncthreads();                                    // bar3

  const char* erow = smem + l15 * 128;
  const unsigned eo0 = ((unsigned)(kg * 16)) ^ swl;
  const unsigned eo1 = ((unsigned)(64 + kg * 16)) ^ swl;
  const float* esqp = (const float*)(smem + R2);

  const float invtau = 1.0f / gtau[0];
  const float4* up4 = (const float4*)(gu + (size_t)n * 4194304
                     + (size_t)(b0 + w * 16 + l15) * 512 + kg * 4);

  // ---- sweep 1: Z, Wk, and Z2' = sum(exp((s+g)/tau)) (lse-free shift) ----
  float Z = 0.f, Wk = 0.f, Z2 = 0.f;
  {
    float4 Pa = up4[0], Pb = up4[4], Pc = up4[8], Pd = up4[12];
#pragma unroll
    for (int t = 0; t < 32; ++t) {
      short8 eb0 = *(const short8*)(erow + t * 2048 + eo0);
      short8 eb1 = *(const short8*)(erow + t * 2048 + eo1);
      float4v d = (float4v){0.f, 0.f, 0.f, 0.f};
      d = __builtin_amdgcn_mfma_f32_16x16x32_bf16(eb0, xb0, d, 0, 0, 0);
      d = __builtin_amdgcn_mfma_f32_16x16x32_bf16(eb1, xb1, d, 0, 0, 0);
      const float4 eq = *(const float4*)(esqp + t * 16 + kg * 4);
      const float s0 = 2.f * d[0] - eq.x;
      const float s1 = 2.f * d[1] - eq.y;
      const float s2 = 2.f * d[2] - eq.z;
      const float s3 = 2.f * d[3] - eq.w;
      const float e0 = __expf(s0), e1 = __expf(s1), e2 = __expf(s2), e3 = __expf(s3);
      Z  += (e0 + e1) + (e2 + e3);
      Wk += e0 * s0 + e1 * s1 + e2 * s2 + e3 * s3;
      const float4 uu = Pa;
      Pa = Pb; Pb = Pc; Pc = Pd;
      if (t < 28) Pd = up4[(t + 4) * 4];
      const float g0 = -__logf(-__logf(uu.x));
      const float g1 = -__logf(-__logf(uu.y));
      const float g2 = -__logf(-__logf(uu.z));
      const float g3 = -__logf(-__logf(uu.w));
      Z2 += __expf((s0 + g0) * invtau) + __expf((s1 + g1) * invtau)
          + __expf((s2 + g2) * invtau) + __expf((s3 + g3) * invtau);
    }
  }
  Z  += __shfl_xor(Z, 16);  Z  += __shfl_xor(Z, 32);
  Wk += __shfl_xor(Wk, 16); Wk += __shfl_xor(Wk, 32);
  Z2 += __shfl_xor(Z2, 16); Z2 += __shfl_xor(Z2, 32);
  const float lse = __logf(Z);
  const float logM = 6.2383246250395075f;
  float klrow = Wk / Z - lse + logM;                  // row KL (dup x4 over kg)
  const float rz2 = 1.0f / Z2;

  // ---- sweep 2 fused with quantize: recompute s,g; lp -> glg; y*rz2 -> LDS ----
  float4v* lp4 = (float4v*)(glg + (size_t)(b0 + w * 16 + l15) * 4096 + n * 512 + kg * 4);
  ushort* sampw = (ushort*)(smem + R2 + 8192 + w * 1024);   // [32 m][16 r]
  const char* sampc = (const char*)sampw;
  const unsigned trA = (unsigned)(uintptr_t)sampw
                     + (unsigned)(kg * 128 + (l15 >> 2) * 32 + (l15 & 3) * 8);
  const int mrow = kg * 4 + (l15 >> 2);
  const unsigned ebase = (unsigned)(uintptr_t)smem + (unsigned)(mrow * 128);
  const unsigned msw = ((unsigned)(mrow & 7)) << 4;
  unsigned trB0 = ebase + ((unsigned)(  0 + (l15 & 3) * 8) ^ msw);
  unsigned trB1 = ebase + ((unsigned)( 32 + (l15 & 3) * 8) ^ msw);
  unsigned trB2 = ebase + ((unsigned)( 64 + (l15 & 3) * 8) ^ msw);
  unsigned trB3 = ebase + ((unsigned)( 96 + (l15 & 3) * 8) ^ msw);

  float4v qacc0 = (float4v){0.f,0.f,0.f,0.f};
  float4v qacc1 = (float4v){0.f,0.f,0.f,0.f};
  float4v qacc2 = (float4v){0.f,0.f,0.f,0.f};
  float4v qacc3 = (float4v){0.f,0.f,0.f,0.f};
  float4v avgA  = (float4v){0.f,0.f,0.f,0.f};
  float4v avgB  = (float4v){0.f,0.f,0.f,0.f};

  float4 P0 = up4[0], P1 = up4[4], P2 = up4[8], P3 = up4[12];
#pragma unroll
  for (int c = 0; c < 16; ++c) {
    const float4 cu0 = P0, cu1 = P1;
    P0 = P2; P1 = P3;
    if (c < 14) { P2 = up4[(2 * c + 4) * 4]; P3 = up4[(2 * c + 5) * 4]; }
#pragma unroll
    for (int th = 0; th < 2; ++th) {
      const int t = c * 2 + th;
      short8 eb0 = *(const short8*)(erow + t * 2048 + eo0);
      short8 eb1 = *(const short8*)(erow + t * 2048 + eo1);
      float4v d = (float4v){0.f, 0.f, 0.f, 0.f};
      d = __builtin_amdgcn_mfma_f32_16x16x32_bf16(eb0, xb0, d, 0, 0, 0);
      d = __builtin_amdgcn_mfma_f32_16x16x32_bf16(eb1, xb1, d, 0, 0, 0);
      const float4 eq = *(const float4*)(esqp + t * 16 + kg * 4);
      const float s0 = 2.f * d[0] - eq.x;
      const float s1 = 2.f * d[1] - eq.y;
      const float s2 = 2.f * d[2] - eq.z;
      const float s3 = 2.f * d[3] - eq.w;
      float4v lpv = { s0 - lse, s1 - lse, s2 - lse, s3 - lse };
      lp4[t * 4] = lpv;
      const float4 uu = (th == 0) ? cu0 : cu1;
      const float g0 = -__logf(-__logf(uu.x));
      const float g1 = -__logf(-__logf(uu.y));
      const float g2 = -__logf(-__logf(uu.z));
      const float g3 = -__logf(-__logf(uu.w));
      const float y0 = __expf((s0 + g0) * invtau) * rz2;
      const float y1 = __expf((s1 + g1) * invtau) * rz2;
      const float y2 = __expf((s2 + g2) * invtau) * rz2;
      const float y3 = __expf((s3 + g3) * invtau) * rz2;
      sampw[(th * 16 + kg * 4 + 0) * 16 + l15] = f2bf(y0);
      sampw[(th * 16 + kg * 4 + 1) * 16 + l15] = f2bf(y1);
      sampw[(th * 16 + kg * 4 + 2) * 16 + l15] = f2bf(y2);
      sampw[(th * 16 + kg * 4 + 3) * 16 + l15] = f2bf(y3);
    }
    asm volatile("s_waitcnt lgkmcnt(0)" ::: "memory");
    __builtin_amdgcn_sched_barrier(0);
    const short8 avA = *(const short8*)(sampc + l15 * 32 + (kg & 1) * 16);
    const short8 avB = *(const short8*)(sampc + 512 + l15 * 32 + (kg & 1) * 16);
    ull alo = tr16<0>(trA),  ahi = tr16<512>(trA);
    ull b0l = tr16<0>(trB0), b0h = tr16<2048>(trB0);
    ull b1l = tr16<0>(trB1), b1h = tr16<2048>(trB1);
    ull b2l = tr16<0>(trB2), b2h = tr16<2048>(trB2);
    ull b3l = tr16<0>(trB3), b3h = tr16<2048>(trB3);
    asm volatile("s_waitcnt lgkmcnt(0)" ::: "memory");
    __builtin_amdgcn_sched_barrier(0);
    const unsigned onv = ((l15 == c) && (kg < 2)) ? 0x3F803F80u : 0u;
    union { unsigned u[4]; short8 v; } bs;
    bs.u[0] = onv; bs.u[1] = onv; bs.u[2] = onv; bs.u[3] = onv;
    short8 aa = mk8(alo, ahi);
    qacc0 = __builtin_amdgcn_mfma_f32_16x16x32_bf16(aa, mk8(b0l, b0h), qacc0, 0, 0, 0);
    qacc1 = __builtin_amdgcn_mfma_f32_16x16x32_bf16(aa, mk8(b1l, b1h), qacc1, 0, 0, 0);
    qacc2 = __builtin_amdgcn_mfma_f32_16x16x32_bf16(aa, mk8(b2l, b2h), qacc2, 0, 0, 0);
    qacc3 = __builtin_amdgcn_mfma_f32_16x16x32_bf16(aa, mk8(b3l, b3h), qacc3, 0, 0, 0);
    avgA  = __builtin_amdgcn_mfma_f32_16x16x32_bf16(avA, bs.v, avgA, 0, 0, 0);
    avgB  = __builtin_amdgcn_mfma_f32_16x16x32_bf16(avB, bs.v, avgB, 0, 0, 0);
    trB0 += 4096; trB1 += 4096; trB2 += 4096; trB3 += 4096;
  }

  // ---- store quantized (row b = kg*4+j, col d = l15) ----
  {
    const size_t qb = (size_t)(b0 + w * 16 + kg * 4) * 512 + n * 64 + l15;
#pragma unroll
    for (int j = 0; j < 4; ++j) {
      gq[qb + (size_t)j * 512 +  0] = qacc0[j];
      gq[qb + (size_t)j * 512 + 16] = qacc1[j];
      gq[qb + (size_t)j * 512 + 32] = qacc2[j];
      gq[qb + (size_t)j * 512 + 48] = qacc3[j];
    }
  }

  // ---- KL full-wave value (rows = l15; dup over kg collapses, not sums) ----
  klrow += __shfl_xor(klrow, 1); klrow += __shfl_xor(klrow, 2);
  klrow += __shfl_xor(klrow, 4); klrow += __shfl_xor(klrow, 8);

  __syncthreads();                                    // bar4: samp + esq + E dead
  float* avgl = (float*)(smem + R2);                  // [8][512]
  float* kls  = (float*)smem;                         // in dead E region
  if (lane == 0) kls[w] = klrow;
  // avgA[j]: m = l15*32 + kg*4 + j ; avgB[j]: m = l15*32 + 16 + kg*4 + j
  *(float4v*)(avgl + w * 512 + l15 * 32 + kg * 4)      = avgA;
  *(float4v*)(avgl + w * 512 + l15 * 32 + 16 + kg * 4) = avgB;
  __syncthreads();                                    // bar5
  {
    float s = 0.f;
#pragma unroll
    for (int ww = 0; ww < 8; ++ww) s += avgl[ww * 512 + tid];
    ws_avg[(size_t)blockIdx.x * 512 + tid] = s;
    if (tid == 0) {
      float k = 0.f;
#pragma unroll
      for (int i = 0; i < 8; ++i) k += kls[i];
      ws_kl[blockIdx.x] = k;
    }
  }
}

extern "C" __global__ void __launch_bounds__(512)
vq_fin(const float* __restrict__ ws_avg, const float* __restrict__ ws_kl,
       float* __restrict__ scal)
{
  __shared__ float red[8];
  const int tid = threadIdx.x, lane = tid & 63, w = tid >> 6;
  float pps = 0.f;
  for (int n = 0; n < 8; ++n) {
    float s = 0.f;
    for (int bt = 0; bt < 64; ++bt) s += ws_avg[(size_t)(n * 64 + bt) * 512 + tid];
    const float avg = s * (1.0f / 8192.0f);
    float term = avg * __logf(avg + 1e-10f);
#pragma unroll
    for (int o = 1; o < 64; o <<= 1) term += __shfl_xor(term, o);
    __syncthreads();
    if (lane == 0) red[w] = term;
    __syncthreads();
    if (tid == 0) {
      float tt = 0.f;
#pragma unroll
      for (int i = 0; i < 8; ++i) tt += red[i];
      pps += __expf(-tt);
    }
  }
  float kv = ws_kl[tid];
#pragma unroll
  for (int o = 1; o < 64; o <<= 1) kv += __shfl_xor(kv, o);
  __syncthreads();
  if (lane == 0) red[w] = kv;
  __syncthreads();
  if (tid == 0) {
    float k = 0.f;
#pragma unroll
    for (int i = 0; i < 8; ++i) k += red[i];
    scal[0] = k * (1.0f / 8192.0f);
    scal[1] = pps;
  }
}

extern "C" void kernel_launch(void* const* d_in, const int* in_sizes, int n_in,
                              void* d_out, int out_size, void* d_ws, size_t ws_size,
                              hipStream_t stream)
{
  const float* gx = (const float*)d_in[0];
  const float* ge = (const float*)d_in[1];
  const float* gu = (const float*)d_in[2];
  const float* gt = (const float*)d_in[3];
  float* out  = (float*)d_out;
  float* gq   = out;
  float* scal = out + 4194304;
  float* glg  = out + 4194306;
  float* ws_avg = (float*)d_ws;
  float* ws_kl  = ws_avg + 512 * 512;

  (void)hipFuncSetAttribute((const void*)vq_main,
                            hipFuncAttributeMaxDynamicSharedMemorySize, LDS_SZ);
  vq_main<<<dim3(512), dim3(512), LDS_SZ, stream>>>(gx, ge, gu, gt, gq, glg, ws_avg, ws_kl);
  vq_fin<<<dim3(1), dim3(512), 0, stream>>>(ws_avg, ws_kl, scal);
}